// Round 1
// 861.701 us; speedup vs baseline: 1.0036x; 1.0036x over previous
//
#include <hip/hip_runtime.h>
#include <hip/hip_bf16.h>
#include <math.h>

#define BSZ 8
#define NLVL 4
#define E 512
#define H 8
#define D 64
#define FFN 2048
#define NNZ 131072
#define NQ 32
#define P32 32
#define NEGF -3.0e38f

typedef __attribute__((ext_vector_type(8))) short bf16x8;
typedef __attribute__((ext_vector_type(4))) float f32x4;

// ws layout (float offsets). ints counts_b[8], off_b[8] at front.
#define WS_QROT   16
#define WS_WSUM   (WS_QROT + NQ*E)
#define WS_OATT   (WS_WSUM + BSZ*P32*E)
#define WS_O2     (WS_OATT + NQ*E)
#define WS_Y      (WS_O2 + NQ*E)
#define WS_HID    (WS_Y + NQ*E)
#define WS_PART   (WS_HID + NQ*FFN)          // [512 chunks][32 p][512 e] f32  (also reused as WkT before k_flash)
#define WS_ML     (WS_PART + 512*P32*E)      // [512][32][2] f32
#define WS_WALL   (WS_ML + 512*P32*2)        // bf16 [b][128][512] (shorts)

__device__ inline short f2bf(float x) {
    __hip_bfloat16 h = __float2bfloat16(x);
    union { __hip_bfloat16 v; short s; } u; u.v = h; return u.s;
}

// ---------------- tiny setup kernels ----------------
__global__ void k_zero(int* wsi) {
    if (blockIdx.x == 0 && threadIdx.x < 8) wsi[threadIdx.x] = 0;
}

__global__ void k_hist(const int* __restrict__ fb, int* wsi) {
    __shared__ int h[8];
    int t = threadIdx.x;
    if (t < 8) h[t] = 0;
    __syncthreads();
    for (int j = blockIdx.x * 256 + t; j < NNZ; j += gridDim.x * 256)
        atomicAdd(&h[fb[j]], 1);
    __syncthreads();
    if (t < 8) atomicAdd(&wsi[t], h[t]);
}

__global__ void k_off(int* wsi) {
    if (threadIdx.x == 0) {
        int run = 0;
        for (int b = 0; b < 8; b++) { wsi[8 + b] = run; run += wsi[b]; }
    }
}

// ---------------- WkT[c][e] = Wkv[e][c]  (K-part only, c < E) ----------------
// Fixes k_wtil's 4KB-lane-stride gather: lanes must run along e.
__global__ void k_tr(const float* __restrict__ Wkv, float* __restrict__ wkt) {
    __shared__ float tile[64][65];
    int ct = blockIdx.x & 7, et = blockIdx.x >> 3;
    int t = threadIdx.x;
    int tc = t & 63, tr = t >> 6;
#pragma unroll
    for (int i = 0; i < 16; i++) {
        int e = et * 64 + tr + i * 4;
        tile[tr + i * 4][tc] = Wkv[(size_t)e * (2 * E) + ct * 64 + tc];
    }
    __syncthreads();
#pragma unroll
    for (int i = 0; i < 16; i++) {
        int c = tr + i * 4;
        wkt[(size_t)(ct * 64 + c) * E + et * 64 + tc] = tile[tc][c];
    }
}

// ---------------- q = rope(LN(bg) @ Wq) ----------------
__global__ void k_qrot(const float* __restrict__ bg, const float* __restrict__ Wq,
                       const float* __restrict__ rf, const float* __restrict__ g,
                       const float* __restrict__ bb, float* __restrict__ ws) {
    __shared__ float xr[E];
    __shared__ float qrow[E];
    __shared__ float red[8];
    int r = blockIdx.x, t = threadIdx.x;
    float v0 = bg[r * E + t], v1 = bg[r * E + t + 256];
    float s = v0 + v1;
    for (int o = 32; o > 0; o >>= 1) s += __shfl_down(s, o, 64);
    if ((t & 63) == 0) red[t >> 6] = s;
    __syncthreads();
    if (t == 0) red[0] = (red[0] + red[1] + red[2] + red[3]) * (1.0f / E);
    __syncthreads();
    float mu = red[0];
    __syncthreads();
    float d0 = v0 - mu, d1 = v1 - mu;
    s = d0 * d0 + d1 * d1;
    for (int o = 32; o > 0; o >>= 1) s += __shfl_down(s, o, 64);
    if ((t & 63) == 0) red[t >> 6] = s;
    __syncthreads();
    if (t == 0) red[0] = rsqrtf((red[0] + red[1] + red[2] + red[3]) * (1.0f / E) + 1e-5f);
    __syncthreads();
    float rstd = red[0];
    xr[t] = d0 * rstd * g[t] + bb[t];
    xr[t + 256] = d1 * rstd * g[t + 256] + bb[t + 256];
    __syncthreads();
    for (int half = 0; half < 2; half++) {
        int c = t + half * 256;
        float acc = 0.f;
        for (int e = 0; e < E; e++) acc += xr[e] * Wq[e * E + c];
        qrow[c] = acc;
    }
    __syncthreads();
    int c0 = 2 * t, c1 = c0 + 1;
    int h = c0 >> 6, ii = (c0 & 63) >> 1;
    float freq = rf[h * 32 + ii];
    float pos = (float)(r >> 3);
    float a = pos * freq, ca = cosf(a), sa = sinf(a);
    float x1 = qrow[c0], x2 = qrow[c1];
    float* qr = ws + WS_QROT + r * E;
    qr[c0] = x1 * ca - x2 * sa;
    qr[c1] = x1 * sa + x2 * ca;
}

// ---------------- Wall_bf[b][n=lvl*32+l*8+h][e] ----------------
// Reads WkT (pre-transposed) so lanes are contiguous along e.
__global__ void k_wtil(const float* __restrict__ wkt, const float* __restrict__ rf,
                       const float* __restrict__ ws, short* __restrict__ wall) {
    __shared__ float u[D];
    int blk = blockIdx.x;
    int h = blk & 7, lvl = (blk >> 3) & 3, r = blk >> 5;
    int b = r >> 2, l = r & 3;
    int t = threadIdx.x;
    const float* qr = ws + WS_QROT + r * E + h * D;
    if (t < 32) {
        float freq = rf[h * 32 + t];
        float a = (float)lvl * freq;
        float ca = cosf(a), sa = sinf(a);
        float x1 = qr[2 * t], x2 = qr[2 * t + 1];
        u[2 * t] = x1 * ca + x2 * sa;
        u[2 * t + 1] = -x1 * sa + x2 * ca;
    }
    __syncthreads();
    float acc[8];
#pragma unroll
    for (int i = 0; i < 8; i++) acc[i] = 0.f;
    for (int c = 0; c < D; c++) {
        float uc = u[c];
        const float* wt = wkt + (size_t)(h * D + c) * E + t;
#pragma unroll
        for (int i = 0; i < 8; i++) acc[i] += wt[i * 64] * uc;
    }
    int n = lvl * 32 + l * 8 + h;
    short* wrow_out = wall + ((size_t)(b * 128 + n)) * E;
#pragma unroll
    for (int i = 0; i < 8; i++) wrow_out[t + i * 64] = f2bf(acc[i] * 0.125f);
}

// ---------------- fused flash attention over key chunks ----------------
// Grid (b=8, kc=64 chunks of 256 keys). 256 thr = 4 waves.
// v2: register-prefetch of next sub-step's fv (T14), per-lane softmax state
// (no wave0-serial sections, 4 barriers/sub-step), __expf, setprio around MFMA.
#define KSTR 520   // kbuf e-stride (shorts)
#define TSTR 40    // fvT/pbuf key-stride (shorts)
__global__ __launch_bounds__(256, 2) void k_flash(
    const float* __restrict__ fv, const int* __restrict__ fl,
    const short* __restrict__ wall, const int* __restrict__ wsi,
    const int* __restrict__ maxlen, float* __restrict__ part, float* __restrict__ ml) {
    __shared__ short kbuf[32 * KSTR];    // [key][e] bf16
    __shared__ short fvT[512 * TSTR];    // [e][key] bf16
    __shared__ short pbuf[32 * TSTR];    // [p][key] bf16
    __shared__ float mbuf[4 * 32];
    __shared__ float lpart[4 * 32];

    int t = threadIdx.x;
    int w = t >> 6, lane = t & 63, col = lane & 15, quad = lane >> 4;
    int b = blockIdx.x, kc = blockIdx.y;
    int cnt = wsi[b], mlen = maxlen[0];
    int lim = cnt < mlen ? cnt : mlen;
    int off = wsi[8 + b];
    int kbase = kc * 256;
    int nv = lim - kbase; if (nv > 256) nv = 256; if (nv < 0) nv = 0;

    // per-lane softmax state for planes p = mt*16 + quad*4 + r
    float m_reg[2][4], l_reg[2][4], a_reg[2][4];
#pragma unroll
    for (int mt = 0; mt < 2; mt++)
#pragma unroll
        for (int r = 0; r < 4; r++) { m_reg[mt][r] = NEGF; l_reg[mt][r] = 0.f; }

    f32x4 acc_o[2][8];
#pragma unroll
    for (int mt = 0; mt < 2; mt++)
#pragma unroll
        for (int nt = 0; nt < 8; nt++) acc_o[mt][nt] = f32x4{0.f, 0.f, 0.f, 0.f};

    const short* wallb = wall + (size_t)b * 128 * E;
    int sj = (t & 15) * 2;
    int se = (t >> 4) * 32;

    // ---- register prefetch buffers: 2 rows x 8 float4 ----
    float4 pf0[8], pf1[8];
    if (nv > 0) {
        int g0 = off + kbase + sj, g1 = g0 + 1;
        if (g0 > NNZ - 1) g0 = NNZ - 1;
        if (g1 > NNZ - 1) g1 = NNZ - 1;
        const float* r0 = fv + (size_t)g0 * E + se;
        const float* r1 = fv + (size_t)g1 * E + se;
#pragma unroll
        for (int i = 0; i < 8; i++) {
            pf0[i] = *(const float4*)(r0 + i * 4);
            pf1[i] = *(const float4*)(r1 + i * 4);
        }
    }

    for (int s = 0; s < 8; s++) {
        int vs = nv - s * 32;
        if (vs <= 0) break;
        __syncthreads();   // previous sub-step done reading kbuf/fvT/pbuf
        // ---- S1a: write prefetched regs -> LDS (bf16, two layouts) ----
#pragma unroll
        for (int i = 0; i < 8; i++) {
            float4 x0 = pf0[i], x1 = pf1[i];
            int e = se + i * 4;
            *(__hip_bfloat162*)&kbuf[sj * KSTR + e]           = __float22bfloat162_rn(float2{x0.x, x0.y});
            *(__hip_bfloat162*)&kbuf[sj * KSTR + e + 2]       = __float22bfloat162_rn(float2{x0.z, x0.w});
            *(__hip_bfloat162*)&kbuf[(sj + 1) * KSTR + e]     = __float22bfloat162_rn(float2{x1.x, x1.y});
            *(__hip_bfloat162*)&kbuf[(sj + 1) * KSTR + e + 2] = __float22bfloat162_rn(float2{x1.z, x1.w});
            *(__hip_bfloat162*)&fvT[(e + 0) * TSTR + sj] = __float22bfloat162_rn(float2{x0.x, x1.x});
            *(__hip_bfloat162*)&fvT[(e + 1) * TSTR + sj] = __float22bfloat162_rn(float2{x0.y, x1.y});
            *(__hip_bfloat162*)&fvT[(e + 2) * TSTR + sj] = __float22bfloat162_rn(float2{x0.z, x1.z});
            *(__hip_bfloat162*)&fvT[(e + 3) * TSTR + sj] = __float22bfloat162_rn(float2{x0.w, x1.w});
        }
        // ---- S1b: issue next sub-step's global loads (fly over compute + barriers) ----
        if (nv - (s + 1) * 32 > 0) {
            int g0 = off + kbase + (s + 1) * 32 + sj, g1 = g0 + 1;
            if (g0 > NNZ - 1) g0 = NNZ - 1;
            if (g1 > NNZ - 1) g1 = NNZ - 1;
            const float* r0 = fv + (size_t)g0 * E + se;
            const float* r1 = fv + (size_t)g1 * E + se;
#pragma unroll
            for (int i = 0; i < 8; i++) {
                pf0[i] = *(const float4*)(r0 + i * 4);
                pf1[i] = *(const float4*)(r1 + i * 4);
            }
        }
        // levels for this sub-step (issued early, consumed after scores)
        int kg0 = off + kbase + s * 32 + col;
        int kg1 = kg0 + 16;
        if (kg0 > NNZ - 1) kg0 = NNZ - 1;
        if (kg1 > NNZ - 1) kg1 = NNZ - 1;
        int lv0 = fl[kg0], lv1 = fl[kg1];
        bool valid0 = (s * 32 + col) < nv;
        bool valid1 = (s * 32 + 16 + col) < nv;
        bool sel0 = valid0 && (lv0 == w);
        bool sel1 = valid1 && (lv1 == w);
        __syncthreads();   // staging visible
        // ---- S2: scores MFMA: D[wall-row][key], K=512 ----
        f32x4 acc_s[2][2];
#pragma unroll
        for (int mt = 0; mt < 2; mt++)
#pragma unroll
            for (int kt = 0; kt < 2; kt++) acc_s[mt][kt] = f32x4{0.f, 0.f, 0.f, 0.f};
        {
            const short* wr0 = wallb + (size_t)(w * 32 + col) * E + quad * 8;
            const short* wr1 = wr0 + (size_t)16 * E;
            const short* kb0 = &kbuf[col * KSTR + quad * 8];
            const short* kb1 = &kbuf[(16 + col) * KSTR + quad * 8];
            __builtin_amdgcn_s_setprio(1);
#pragma unroll
            for (int ks = 0; ks < 16; ks++) {
                int e0 = ks * 32;
                bf16x8 A0 = *(const bf16x8*)(wr0 + e0);
                bf16x8 A1 = *(const bf16x8*)(wr1 + e0);
                bf16x8 B0 = *(const bf16x8*)(kb0 + e0);
                bf16x8 B1 = *(const bf16x8*)(kb1 + e0);
                acc_s[0][0] = __builtin_amdgcn_mfma_f32_16x16x32_bf16(A0, B0, acc_s[0][0], 0, 0, 0);
                acc_s[0][1] = __builtin_amdgcn_mfma_f32_16x16x32_bf16(A0, B1, acc_s[0][1], 0, 0, 0);
                acc_s[1][0] = __builtin_amdgcn_mfma_f32_16x16x32_bf16(A1, B0, acc_s[1][0], 0, 0, 0);
                acc_s[1][1] = __builtin_amdgcn_mfma_f32_16x16x32_bf16(A1, B1, acc_s[1][1], 0, 0, 0);
            }
            __builtin_amdgcn_s_setprio(0);
        }
        // ---- S3: per-wave per-plane sub-step max -> mbuf ----
#pragma unroll
        for (int mt = 0; mt < 2; mt++) {
#pragma unroll
            for (int r = 0; r < 4; r++) {
                float v0 = sel0 ? acc_s[mt][0][r] : NEGF;
                float v1 = sel1 ? acc_s[mt][1][r] : NEGF;
                float v = fmaxf(v0, v1);
#pragma unroll
                for (int msk = 1; msk < 16; msk <<= 1) v = fmaxf(v, __shfl_xor(v, msk, 16));
                if (col == 0) mbuf[w * 32 + mt * 16 + quad * 4 + r] = v;
            }
        }
        __syncthreads();   // mbuf visible
        // ---- S4: per-lane combine across the 4 waves (redundant, branch-free) ----
#pragma unroll
        for (int mt = 0; mt < 2; mt++)
#pragma unroll
            for (int r = 0; r < 4; r++) {
                int p = mt * 16 + quad * 4 + r;
                float mo = m_reg[mt][r];
                float mn = fmaxf(mo, fmaxf(fmaxf(mbuf[p], mbuf[32 + p]),
                                           fmaxf(mbuf[64 + p], mbuf[96 + p])));
                a_reg[mt][r] = __expf(mo - mn);
                m_reg[mt][r] = mn;
            }
        // ---- S5: P~ = exp(s - m) -> pbuf; per-wave partial l; rescale O ----
#pragma unroll
        for (int mt = 0; mt < 2; mt++) {
#pragma unroll
            for (int r = 0; r < 4; r++) {
                int p = mt * 16 + quad * 4 + r;
                float ls = 0.f;
                if (sel0) {
                    float pv = __expf(acc_s[mt][0][r] - m_reg[mt][r]);
                    pbuf[p * TSTR + col] = f2bf(pv);
                    ls += pv;
                } else if (w == 0 && !valid0) {
                    pbuf[p * TSTR + col] = 0;
                }
                if (sel1) {
                    float pv = __expf(acc_s[mt][1][r] - m_reg[mt][r]);
                    pbuf[p * TSTR + 16 + col] = f2bf(pv);
                    ls += pv;
                } else if (w == 0 && !valid1) {
                    pbuf[p * TSTR + 16 + col] = 0;
                }
#pragma unroll
                for (int msk = 1; msk < 16; msk <<= 1) ls += __shfl_xor(ls, msk, 16);
                if (col == 0) lpart[w * 32 + p] = ls;
            }
        }
#pragma unroll
        for (int mt = 0; mt < 2; mt++)
#pragma unroll
            for (int nt = 0; nt < 8; nt++)
#pragma unroll
                for (int r = 0; r < 4; r++) acc_o[mt][nt][r] *= a_reg[mt][r];
        __syncthreads();   // pbuf + lpart visible
        // ---- S6: PV MFMA: O[p][e] += P~ @ fvT, K=32 keys ----
        {
            bf16x8 Ap0 = *(const bf16x8*)&pbuf[col * TSTR + quad * 8];
            bf16x8 Ap1 = *(const bf16x8*)&pbuf[(16 + col) * TSTR + quad * 8];
            const short* bt = &fvT[(size_t)(w * 128 + col) * TSTR + quad * 8];
            __builtin_amdgcn_s_setprio(1);
#pragma unroll
            for (int nt = 0; nt < 8; nt++) {
                bf16x8 Bf = *(const bf16x8*)(bt + (size_t)nt * 16 * TSTR);
                acc_o[0][nt] = __builtin_amdgcn_mfma_f32_16x16x32_bf16(Ap0, Bf, acc_o[0][nt], 0, 0, 0);
                acc_o[1][nt] = __builtin_amdgcn_mfma_f32_16x16x32_bf16(Ap1, Bf, acc_o[1][nt], 0, 0, 0);
            }
            __builtin_amdgcn_s_setprio(0);
        }
        // ---- S7: per-lane running l update (lpart stable until next S5, 3 barriers away) ----
#pragma unroll
        for (int mt = 0; mt < 2; mt++)
#pragma unroll
            for (int r = 0; r < 4; r++) {
                int p = mt * 16 + quad * 4 + r;
                l_reg[mt][r] = l_reg[mt][r] * a_reg[mt][r] +
                               (lpart[p] + lpart[32 + p] + lpart[64 + p] + lpart[96 + p]);
            }
    }
    // ---- epilogue: write partial O and (m,l) ----
    size_t pbase = ((size_t)(b * 64 + kc) * P32) * E;
#pragma unroll
    for (int mt = 0; mt < 2; mt++)
#pragma unroll
        for (int r = 0; r < 4; r++) {
            int p = mt * 16 + quad * 4 + r;
#pragma unroll
            for (int nt = 0; nt < 8; nt++) {
                int e = w * 128 + nt * 16 + col;
                part[pbase + (size_t)p * E + e] = acc_o[mt][nt][r];
            }
        }
    if (w == 0 && col == 0) {
#pragma unroll
        for (int mt = 0; mt < 2; mt++)
#pragma unroll
            for (int r = 0; r < 4; r++) {
                int p = mt * 16 + quad * 4 + r;
                size_t idx = (size_t)(b * 64 + kc) * P32 + p;
                ml[idx * 2] = m_reg[mt][r];
                ml[idx * 2 + 1] = l_reg[mt][r];
            }
    }
}

// ---------------- merge chunk partials (log-sum-exp) -> wsum[b*32+p][e] ----------------
__global__ void k_merge(const float* __restrict__ part, const float* __restrict__ ml,
                        float* __restrict__ wsum) {
    __shared__ float wexp[64];
    int b = blockIdx.x >> 5, p = blockIdx.x & 31;
    int t = threadIdx.x;
    float M = NEGF;
    for (int kc = 0; kc < 64; kc++)
        M = fmaxf(M, ml[((size_t)(b * 64 + kc) * P32 + p) * 2]);
    float denom = 0.f;
    for (int kc = 0; kc < 64; kc++) {
        size_t idx = ((size_t)(b * 64 + kc) * P32 + p) * 2;
        denom += ml[idx + 1] * expf(ml[idx] - M);
    }
    if (t < 64)
        wexp[t] = expf(ml[((size_t)(b * 64 + t) * P32 + p) * 2] - M);
    __syncthreads();
    float inv = 1.0f / denom;
    for (int half = 0; half < 2; half++) {
        int e = t + half * 256;
        float acc = 0.f;
        for (int kc = 0; kc < 64; kc++)
            acc += part[((size_t)(b * 64 + kc) * P32 + p) * E + e] * wexp[kc];
        wsum[((size_t)(b * P32 + p)) * E + e] = acc * inv;
    }
}

// ---------------- o_attn[r][c] = wsum[b][l*8+h] . Wv[:, h*64+ch] ----------------
__global__ void k_oproj(const float* __restrict__ wsum, const float* __restrict__ Wkv,
                        float* __restrict__ oatt) {
    __shared__ float Aw[NQ][E];
    int h = blockIdx.x >> 2, ct = blockIdx.x & 3;
    int t = threadIdx.x;
    {
        int rr = t >> 3, x = (t & 7) * 64;
        int row = (rr >> 2) * P32 + (rr & 3) * 8 + h;
#pragma unroll
        for (int q4 = 0; q4 < 16; q4++)
            *(float4*)&Aw[rr][x + q4 * 4] = *(const float4*)&wsum[(size_t)row * E + x + q4 * 4];
    }
    __syncthreads();
#pragma unroll
    for (int rep = 0; rep < 2; rep++) {
        int idx = rep * 256 + t;
        int rr = idx >> 4, cl = idx & 15;
        int c = h * D + ct * 16 + cl;
        float acc = 0.f;
        for (int e = 0; e < E; e++) acc += Aw[rr][e] * Wkv[(size_t)e * (2 * E) + E + c];
        oatt[rr * E + c] = acc;
    }
}

// ---------------- o2 = o_attn @ Wo + bg ----------------
__global__ void k_wo(const float* __restrict__ oatt, const float* __restrict__ Wo,
                     const float* __restrict__ bg, float* __restrict__ o2) {
    __shared__ float Aw[NQ * E];
    int t = threadIdx.x;
#pragma unroll
    for (int q = 0; q < 16; q++) {
        int i = (q * 256 + t) * 4;
        *(float4*)&Aw[i] = *(const float4*)&oatt[i];
    }
    __syncthreads();
    int ct = blockIdx.x;
#pragma unroll
    for (int rep = 0; rep < 4; rep++) {
        int idx = rep * 256 + t;
        int rr = idx >> 5, cl = idx & 31;
        int c = ct * 32 + cl;
        float acc = bg[rr * E + c];
        for (int e = 0; e < E; e++) acc += Aw[rr * E + e] * Wo[(size_t)e * E + c];
        o2[rr * E + c] = acc;
    }
}

// ---------------- LN rows of o2 -> y ----------------
__global__ void k_ln2(const float* __restrict__ o2, const float* __restrict__ g,
                      const float* __restrict__ bb, float* __restrict__ y) {
    __shared__ float red[8];
    int r = blockIdx.x, t = threadIdx.x;
    float v0 = o2[r * E + t], v1 = o2[r * E + t + 256];
    float s = v0 + v1;
    for (int o = 32; o > 0; o >>= 1) s += __shfl_down(s, o, 64);
    if ((t & 63) == 0) red[t >> 6] = s;
    __syncthreads();
    if (t == 0) red[0] = (red[0] + red[1] + red[2] + red[3]) * (1.0f / E);
    __syncthreads();
    float mu = red[0];
    __syncthreads();
    float d0 = v0 - mu, d1 = v1 - mu;
    s = d0 * d0 + d1 * d1;
    for (int o = 32; o > 0; o >>= 1) s += __shfl_down(s, o, 64);
    if ((t & 63) == 0) red[t >> 6] = s;
    __syncthreads();
    if (t == 0) red[0] = rsqrtf((red[0] + red[1] + red[2] + red[3]) * (1.0f / E) + 1e-5f);
    __syncthreads();
    float rstd = red[0];
    y[r * E + t] = d0 * rstd * g[t] + bb[t];
    y[r * E + t + 256] = d1 * rstd * g[t + 256] + bb[t + 256];
}

// ---------------- hid = relu(y @ W1 + b1) ----------------
__global__ void k_ffn1(const float* __restrict__ y, const float* __restrict__ W1,
                       const float* __restrict__ b1, float* __restrict__ hid) {
    __shared__ float Aw[NQ * E];
    int t = threadIdx.x;
#pragma unroll
    for (int q = 0; q < 16; q++) {
        int i = (q * 256 + t) * 4;
        *(float4*)&Aw[i] = *(const float4*)&y[i];
    }
    __syncthreads();
    int ft = blockIdx.x;
#pragma unroll
    for (int rep = 0; rep < 4; rep++) {
        int idx = rep * 256 + t;
        int rr = idx >> 5, fl = idx & 31;
        int f = ft * 32 + fl;
        float acc = b1[f];
        for (int e = 0; e < E; e++) acc += Aw[rr * E + e] * W1[(size_t)e * FFN + f];
        hid[rr * FFN + f] = fmaxf(acc, 0.f);
    }
}

// ---------------- out = o2 + hid @ W2 + b2 ----------------
__global__ void k_ffn2(const float* __restrict__ hid, const float* __restrict__ W2,
                       const float* __restrict__ b2, const float* __restrict__ o2,
                       float* __restrict__ out) {
    int ct = blockIdx.x;
    int t = threadIdx.x;
#pragma unroll
    for (int rep = 0; rep < 2; rep++) {
        int idx = rep * 256 + t;
        int rr = idx >> 4, cl = idx & 15;
        int c = ct * 16 + cl;
        float acc = b2[c] + o2[rr * E + c];
        for (int f = 0; f < FFN; f++) acc += hid[rr * FFN + f] * W2[(size_t)f * E + c];
        out[rr * E + c] = acc;
    }
}

extern "C" void kernel_launch(void* const* d_in, const int* in_sizes, int n_in,
                              void* d_out, int out_size, void* d_ws, size_t ws_size,
                              hipStream_t stream) {
    const float* bg  = (const float*)d_in[0];
    const float* fv  = (const float*)d_in[1];
    const int*   fb  = (const int*)d_in[2];
    const int*   fl  = (const int*)d_in[3];
    const float* Wq  = (const float*)d_in[4];
    const float* Wkv = (const float*)d_in[5];
    const float* Wo  = (const float*)d_in[6];
    const float* rf  = (const float*)d_in[7];
    const float* lag = (const float*)d_in[8];
    const float* lab = (const float*)d_in[9];
    const float* lfg = (const float*)d_in[10];
    const float* lfb = (const float*)d_in[11];
    const float* W1  = (const float*)d_in[12];
    const float* b1  = (const float*)d_in[13];
    const float* W2  = (const float*)d_in[14];
    const float* b2  = (const float*)d_in[15];
    const int* maxlen = (const int*)d_in[16];
    float* ws = (float*)d_ws;
    int* wsi = (int*)d_ws;
    short* wall = (short*)(ws + WS_WALL);
    float* wkt = ws + WS_PART;   // WkT lives in the (not-yet-used) part region
    float* out = (float*)d_out;

    hipLaunchKernelGGL(k_zero, dim3(1), dim3(64), 0, stream, wsi);
    hipLaunchKernelGGL(k_hist, dim3(128), dim3(256), 0, stream, fb, wsi);
    hipLaunchKernelGGL(k_off, dim3(1), dim3(64), 0, stream, wsi);
    hipLaunchKernelGGL(k_tr, dim3(64), dim3(256), 0, stream, Wkv, wkt);
    hipLaunchKernelGGL(k_qrot, dim3(NQ), dim3(256), 0, stream, bg, Wq, rf, lag, lab, ws);
    hipLaunchKernelGGL(k_wtil, dim3(NQ * NLVL * H), dim3(64), 0, stream, wkt, rf, ws, wall);
    hipLaunchKernelGGL(k_flash, dim3(BSZ, 64), dim3(256), 0, stream,
                       fv, fl, wall, wsi, maxlen, ws + WS_PART, ws + WS_ML);
    hipLaunchKernelGGL(k_merge, dim3(BSZ * P32), dim3(256), 0, stream,
                       ws + WS_PART, ws + WS_ML, ws + WS_WSUM);
    hipLaunchKernelGGL(k_oproj, dim3(H * 4), dim3(256), 0, stream,
                       ws + WS_WSUM, Wkv, ws + WS_OATT);
    hipLaunchKernelGGL(k_wo, dim3(16), dim3(256), 0, stream,
                       ws + WS_OATT, Wo, bg, ws + WS_O2);
    hipLaunchKernelGGL(k_ln2, dim3(NQ), dim3(256), 0, stream,
                       ws + WS_O2, lfg, lfb, ws + WS_Y);
    hipLaunchKernelGGL(k_ffn1, dim3(FFN / 32), dim3(256), 0, stream,
                       ws + WS_Y, W1, b1, ws + WS_HID);
    hipLaunchKernelGGL(k_ffn2, dim3(E / 16), dim3(256), 0, stream,
                       ws + WS_HID, W2, b2, ws + WS_O2, out);
}

// Round 2
// 763.235 us; speedup vs baseline: 1.1330x; 1.1290x over previous
//
#include <hip/hip_runtime.h>
#include <hip/hip_bf16.h>
#include <math.h>

#define BSZ 8
#define NLVL 4
#define E 512
#define H 8
#define D 64
#define FFN 2048
#define NNZ 131072
#define NQ 32
#define P32 32
#define NEGF -3.0e38f

typedef __attribute__((ext_vector_type(8))) short bf16x8;
typedef __attribute__((ext_vector_type(4))) float f32x4;

// ws layout (float offsets). ints counts_b[8], off_b[8] at front.
#define WS_QROT   16
#define WS_WSUM   (WS_QROT + NQ*E)
#define WS_OATT   (WS_WSUM + BSZ*P32*E)
#define WS_O2     (WS_OATT + NQ*E)
#define WS_Y      (WS_O2 + NQ*E)
#define WS_HID    (WS_Y + NQ*E)
#define WS_PART   (WS_HID + NQ*FFN)          // [512 chunks][32 p][512 e] f32  (also reused as WkT before k_flash)
#define WS_ML     (WS_PART + 512*P32*E)      // [512][32][2] f32
#define WS_WALL   (WS_ML + 512*P32*2)        // bf16 [b][128][512] (shorts)

__device__ inline short f2bf(float x) {
    __hip_bfloat16 h = __float2bfloat16(x);
    union { __hip_bfloat16 v; short s; } u; u.v = h; return u.s;
}

// ---------------- tiny setup kernels ----------------
__global__ void k_zero(int* wsi) {
    if (blockIdx.x == 0 && threadIdx.x < 8) wsi[threadIdx.x] = 0;
}

__global__ void k_hist(const int* __restrict__ fb, int* wsi) {
    __shared__ int h[8];
    int t = threadIdx.x;
    if (t < 8) h[t] = 0;
    __syncthreads();
    for (int j = blockIdx.x * 256 + t; j < NNZ; j += gridDim.x * 256)
        atomicAdd(&h[fb[j]], 1);
    __syncthreads();
    if (t < 8) atomicAdd(&wsi[t], h[t]);
}

__global__ void k_off(int* wsi) {
    if (threadIdx.x == 0) {
        int run = 0;
        for (int b = 0; b < 8; b++) { wsi[8 + b] = run; run += wsi[b]; }
    }
}

// ---------------- WkT[c][e] = Wkv[e][c]  (K-part only, c < E) ----------------
__global__ void k_tr(const float* __restrict__ Wkv, float* __restrict__ wkt) {
    __shared__ float tile[64][65];
    int ct = blockIdx.x & 7, et = blockIdx.x >> 3;
    int t = threadIdx.x;
    int tc = t & 63, tr = t >> 6;
#pragma unroll
    for (int i = 0; i < 16; i++) {
        int e = et * 64 + tr + i * 4;
        tile[tr + i * 4][tc] = Wkv[(size_t)e * (2 * E) + ct * 64 + tc];
    }
    __syncthreads();
#pragma unroll
    for (int i = 0; i < 16; i++) {
        int c = tr + i * 4;
        wkt[(size_t)(ct * 64 + c) * E + et * 64 + tc] = tile[tc][c];
    }
}

// ---------------- q = rope(LN(bg) @ Wq) ----------------
__global__ void k_qrot(const float* __restrict__ bg, const float* __restrict__ Wq,
                       const float* __restrict__ rf, const float* __restrict__ g,
                       const float* __restrict__ bb, float* __restrict__ ws) {
    __shared__ float xr[E];
    __shared__ float qrow[E];
    __shared__ float red[8];
    int r = blockIdx.x, t = threadIdx.x;
    float v0 = bg[r * E + t], v1 = bg[r * E + t + 256];
    float s = v0 + v1;
    for (int o = 32; o > 0; o >>= 1) s += __shfl_down(s, o, 64);
    if ((t & 63) == 0) red[t >> 6] = s;
    __syncthreads();
    if (t == 0) red[0] = (red[0] + red[1] + red[2] + red[3]) * (1.0f / E);
    __syncthreads();
    float mu = red[0];
    __syncthreads();
    float d0 = v0 - mu, d1 = v1 - mu;
    s = d0 * d0 + d1 * d1;
    for (int o = 32; o > 0; o >>= 1) s += __shfl_down(s, o, 64);
    if ((t & 63) == 0) red[t >> 6] = s;
    __syncthreads();
    if (t == 0) red[0] = rsqrtf((red[0] + red[1] + red[2] + red[3]) * (1.0f / E) + 1e-5f);
    __syncthreads();
    float rstd = red[0];
    xr[t] = d0 * rstd * g[t] + bb[t];
    xr[t + 256] = d1 * rstd * g[t + 256] + bb[t + 256];
    __syncthreads();
    for (int half = 0; half < 2; half++) {
        int c = t + half * 256;
        float acc = 0.f;
        for (int e = 0; e < E; e++) acc += xr[e] * Wq[e * E + c];
        qrow[c] = acc;
    }
    __syncthreads();
    int c0 = 2 * t, c1 = c0 + 1;
    int h = c0 >> 6, ii = (c0 & 63) >> 1;
    float freq = rf[h * 32 + ii];
    float pos = (float)(r >> 3);
    float a = pos * freq, ca = cosf(a), sa = sinf(a);
    float x1 = qrow[c0], x2 = qrow[c1];
    float* qr = ws + WS_QROT + r * E;
    qr[c0] = x1 * ca - x2 * sa;
    qr[c1] = x1 * sa + x2 * ca;
}

// ---------------- Wall_bf[b][n=lvl*32+l*8+h][e] ----------------
__global__ void k_wtil(const float* __restrict__ wkt, const float* __restrict__ rf,
                       const float* __restrict__ ws, short* __restrict__ wall) {
    __shared__ float u[D];
    int blk = blockIdx.x;
    int h = blk & 7, lvl = (blk >> 3) & 3, r = blk >> 5;
    int b = r >> 2, l = r & 3;
    int t = threadIdx.x;
    const float* qr = ws + WS_QROT + r * E + h * D;
    if (t < 32) {
        float freq = rf[h * 32 + t];
        float a = (float)lvl * freq;
        float ca = cosf(a), sa = sinf(a);
        float x1 = qr[2 * t], x2 = qr[2 * t + 1];
        u[2 * t] = x1 * ca + x2 * sa;
        u[2 * t + 1] = -x1 * sa + x2 * ca;
    }
    __syncthreads();
    float acc[8];
#pragma unroll
    for (int i = 0; i < 8; i++) acc[i] = 0.f;
    for (int c = 0; c < D; c++) {
        float uc = u[c];
        const float* wt = wkt + (size_t)(h * D + c) * E + t;
#pragma unroll
        for (int i = 0; i < 8; i++) acc[i] += wt[i * 64] * uc;
    }
    int n = lvl * 32 + l * 8 + h;
    short* wrow_out = wall + ((size_t)(b * 128 + n)) * E;
#pragma unroll
    for (int i = 0; i < 8; i++) wrow_out[t + i * 64] = f2bf(acc[i] * 0.125f);
}

// ---------------- fused flash attention over key chunks ----------------
#define KSTR 520   // kbuf e-stride (shorts)
#define TSTR 40    // fvT/pbuf key-stride (shorts)
__global__ __launch_bounds__(256, 2) void k_flash(
    const float* __restrict__ fv, const int* __restrict__ fl,
    const short* __restrict__ wall, const int* __restrict__ wsi,
    const int* __restrict__ maxlen, float* __restrict__ part, float* __restrict__ ml) {
    __shared__ short kbuf[32 * KSTR];    // [key][e] bf16
    __shared__ short fvT[512 * TSTR];    // [e][key] bf16
    __shared__ short pbuf[32 * TSTR];    // [p][key] bf16
    __shared__ float mbuf[4 * 32];
    __shared__ float lpart[4 * 32];

    int t = threadIdx.x;
    int w = t >> 6, lane = t & 63, col = lane & 15, quad = lane >> 4;
    int b = blockIdx.x, kc = blockIdx.y;
    int cnt = wsi[b], mlen = maxlen[0];
    int lim = cnt < mlen ? cnt : mlen;
    int off = wsi[8 + b];
    int kbase = kc * 256;
    int nv = lim - kbase; if (nv > 256) nv = 256; if (nv < 0) nv = 0;

    float m_reg[2][4], l_reg[2][4], a_reg[2][4];
#pragma unroll
    for (int mt = 0; mt < 2; mt++)
#pragma unroll
        for (int r = 0; r < 4; r++) { m_reg[mt][r] = NEGF; l_reg[mt][r] = 0.f; }

    f32x4 acc_o[2][8];
#pragma unroll
    for (int mt = 0; mt < 2; mt++)
#pragma unroll
        for (int nt = 0; nt < 8; nt++) acc_o[mt][nt] = f32x4{0.f, 0.f, 0.f, 0.f};

    const short* wallb = wall + (size_t)b * 128 * E;
    int sj = (t & 15) * 2;
    int se = (t >> 4) * 32;

    for (int s = 0; s < 8; s++) {
        int vs = nv - s * 32;
        if (vs <= 0) break;
        // ---- batch-issue this sub-step's 16 fv loads + fl loads (before barrier) ----
        float4 x0[8], x1[8];
        {
            int g0 = off + kbase + s * 32 + sj, g1 = g0 + 1;
            if (g0 > NNZ - 1) g0 = NNZ - 1;
            if (g1 > NNZ - 1) g1 = NNZ - 1;
            const float* r0 = fv + (size_t)g0 * E + se;
            const float* r1 = fv + (size_t)g1 * E + se;
#pragma unroll
            for (int i = 0; i < 8; i++) {
                x0[i] = *(const float4*)(r0 + i * 4);
                x1[i] = *(const float4*)(r1 + i * 4);
            }
        }
        int kg0 = off + kbase + s * 32 + col;
        int kg1 = kg0 + 16;
        if (kg0 > NNZ - 1) kg0 = NNZ - 1;
        if (kg1 > NNZ - 1) kg1 = NNZ - 1;
        int lv0 = fl[kg0], lv1 = fl[kg1];
        bool valid0 = (s * 32 + col) < nv;
        bool valid1 = (s * 32 + 16 + col) < nv;
        bool sel0 = valid0 && (lv0 == w);
        bool sel1 = valid1 && (lv1 == w);
        __syncthreads();   // previous sub-step done reading kbuf/fvT/pbuf
        // ---- S1: convert + write to LDS (bf16, two layouts) ----
#pragma unroll
        for (int i = 0; i < 8; i++) {
            float4 v0 = x0[i], v1 = x1[i];
            int e = se + i * 4;
            *(__hip_bfloat162*)&kbuf[sj * KSTR + e]           = __float22bfloat162_rn(float2{v0.x, v0.y});
            *(__hip_bfloat162*)&kbuf[sj * KSTR + e + 2]       = __float22bfloat162_rn(float2{v0.z, v0.w});
            *(__hip_bfloat162*)&kbuf[(sj + 1) * KSTR + e]     = __float22bfloat162_rn(float2{v1.x, v1.y});
            *(__hip_bfloat162*)&kbuf[(sj + 1) * KSTR + e + 2] = __float22bfloat162_rn(float2{v1.z, v1.w});
            *(__hip_bfloat162*)&fvT[(e + 0) * TSTR + sj] = __float22bfloat162_rn(float2{v0.x, v1.x});
            *(__hip_bfloat162*)&fvT[(e + 1) * TSTR + sj] = __float22bfloat162_rn(float2{v0.y, v1.y});
            *(__hip_bfloat162*)&fvT[(e + 2) * TSTR + sj] = __float22bfloat162_rn(float2{v0.z, v1.z});
            *(__hip_bfloat162*)&fvT[(e + 3) * TSTR + sj] = __float22bfloat162_rn(float2{v0.w, v1.w});
        }
        __syncthreads();   // staging visible
        // ---- S2: scores MFMA: D[wall-row][key], K=512 ----
        f32x4 acc_s[2][2];
#pragma unroll
        for (int mt = 0; mt < 2; mt++)
#pragma unroll
            for (int kt = 0; kt < 2; kt++) acc_s[mt][kt] = f32x4{0.f, 0.f, 0.f, 0.f};
        {
            const short* wr0 = wallb + (size_t)(w * 32 + col) * E + quad * 8;
            const short* wr1 = wr0 + (size_t)16 * E;
            const short* kb0 = &kbuf[col * KSTR + quad * 8];
            const short* kb1 = &kbuf[(16 + col) * KSTR + quad * 8];
            __builtin_amdgcn_s_setprio(1);
#pragma unroll
            for (int ks = 0; ks < 16; ks++) {
                int e0 = ks * 32;
                bf16x8 A0 = *(const bf16x8*)(wr0 + e0);
                bf16x8 A1 = *(const bf16x8*)(wr1 + e0);
                bf16x8 B0 = *(const bf16x8*)(kb0 + e0);
                bf16x8 B1 = *(const bf16x8*)(kb1 + e0);
                acc_s[0][0] = __builtin_amdgcn_mfma_f32_16x16x32_bf16(A0, B0, acc_s[0][0], 0, 0, 0);
                acc_s[0][1] = __builtin_amdgcn_mfma_f32_16x16x32_bf16(A0, B1, acc_s[0][1], 0, 0, 0);
                acc_s[1][0] = __builtin_amdgcn_mfma_f32_16x16x32_bf16(A1, B0, acc_s[1][0], 0, 0, 0);
                acc_s[1][1] = __builtin_amdgcn_mfma_f32_16x16x32_bf16(A1, B1, acc_s[1][1], 0, 0, 0);
            }
            __builtin_amdgcn_s_setprio(0);
        }
        // ---- S3: per-wave per-plane sub-step max -> mbuf ----
#pragma unroll
        for (int mt = 0; mt < 2; mt++) {
#pragma unroll
            for (int r = 0; r < 4; r++) {
                float v0 = sel0 ? acc_s[mt][0][r] : NEGF;
                float v1 = sel1 ? acc_s[mt][1][r] : NEGF;
                float v = fmaxf(v0, v1);
#pragma unroll
                for (int msk = 1; msk < 16; msk <<= 1) v = fmaxf(v, __shfl_xor(v, msk, 16));
                if (col == 0) mbuf[w * 32 + mt * 16 + quad * 4 + r] = v;
            }
        }
        __syncthreads();   // mbuf visible
        // ---- S4: per-lane combine across the 4 waves ----
#pragma unroll
        for (int mt = 0; mt < 2; mt++)
#pragma unroll
            for (int r = 0; r < 4; r++) {
                int p = mt * 16 + quad * 4 + r;
                float mo = m_reg[mt][r];
                float mn = fmaxf(mo, fmaxf(fmaxf(mbuf[p], mbuf[32 + p]),
                                           fmaxf(mbuf[64 + p], mbuf[96 + p])));
                a_reg[mt][r] = __expf(mo - mn);
                m_reg[mt][r] = mn;
            }
        // ---- S5: P~ = exp(s - m) -> pbuf; per-wave partial l; rescale O ----
#pragma unroll
        for (int mt = 0; mt < 2; mt++) {
#pragma unroll
            for (int r = 0; r < 4; r++) {
                int p = mt * 16 + quad * 4 + r;
                float ls = 0.f;
                if (sel0) {
                    float pv = __expf(acc_s[mt][0][r] - m_reg[mt][r]);
                    pbuf[p * TSTR + col] = f2bf(pv);
                    ls += pv;
                } else if (w == 0 && !valid0) {
                    pbuf[p * TSTR + col] = 0;
                }
                if (sel1) {
                    float pv = __expf(acc_s[mt][1][r] - m_reg[mt][r]);
                    pbuf[p * TSTR + 16 + col] = f2bf(pv);
                    ls += pv;
                } else if (w == 0 && !valid1) {
                    pbuf[p * TSTR + 16 + col] = 0;
                }
#pragma unroll
                for (int msk = 1; msk < 16; msk <<= 1) ls += __shfl_xor(ls, msk, 16);
                if (col == 0) lpart[w * 32 + p] = ls;
            }
        }
#pragma unroll
        for (int mt = 0; mt < 2; mt++)
#pragma unroll
            for (int nt = 0; nt < 8; nt++)
#pragma unroll
                for (int r = 0; r < 4; r++) acc_o[mt][nt][r] *= a_reg[mt][r];
        __syncthreads();   // pbuf + lpart visible
        // ---- S6: PV MFMA: O[p][e] += P~ @ fvT, K=32 keys ----
        {
            bf16x8 Ap0 = *(const bf16x8*)&pbuf[col * TSTR + quad * 8];
            bf16x8 Ap1 = *(const bf16x8*)&pbuf[(16 + col) * TSTR + quad * 8];
            const short* bt = &fvT[(size_t)(w * 128 + col) * TSTR + quad * 8];
            __builtin_amdgcn_s_setprio(1);
#pragma unroll
            for (int nt = 0; nt < 8; nt++) {
                bf16x8 Bf = *(const bf16x8*)(bt + (size_t)nt * 16 * TSTR);
                acc_o[0][nt] = __builtin_amdgcn_mfma_f32_16x16x32_bf16(Ap0, Bf, acc_o[0][nt], 0, 0, 0);
                acc_o[1][nt] = __builtin_amdgcn_mfma_f32_16x16x32_bf16(Ap1, Bf, acc_o[1][nt], 0, 0, 0);
            }
            __builtin_amdgcn_s_setprio(0);
        }
        // ---- S7: per-lane running l update ----
#pragma unroll
        for (int mt = 0; mt < 2; mt++)
#pragma unroll
            for (int r = 0; r < 4; r++) {
                int p = mt * 16 + quad * 4 + r;
                l_reg[mt][r] = l_reg[mt][r] * a_reg[mt][r] +
                               (lpart[p] + lpart[32 + p] + lpart[64 + p] + lpart[96 + p]);
            }
    }
    // ---- epilogue: write partial O and (m,l) ----
    size_t pbase = ((size_t)(b * 64 + kc) * P32) * E;
#pragma unroll
    for (int mt = 0; mt < 2; mt++)
#pragma unroll
        for (int r = 0; r < 4; r++) {
            int p = mt * 16 + quad * 4 + r;
#pragma unroll
            for (int nt = 0; nt < 8; nt++) {
                int e = w * 128 + nt * 16 + col;
                part[pbase + (size_t)p * E + e] = acc_o[mt][nt][r];
            }
        }
    if (w == 0 && col == 0) {
#pragma unroll
        for (int mt = 0; mt < 2; mt++)
#pragma unroll
            for (int r = 0; r < 4; r++) {
                int p = mt * 16 + quad * 4 + r;
                size_t idx = (size_t)(b * 64 + kc) * P32 + p;
                ml[idx * 2] = m_reg[mt][r];
                ml[idx * 2 + 1] = l_reg[mt][r];
            }
    }
}

// ---------------- merge chunk partials -> wsum[b*32+p][e] (XCD-matched remap) ----------------
__global__ void k_merge(const float* __restrict__ part, const float* __restrict__ ml,
                        float* __restrict__ wsum) {
    __shared__ float wexp[64];
    int b = blockIdx.x & 7, p = blockIdx.x >> 3;
    int t = threadIdx.x;
    float M = NEGF;
    for (int kc = 0; kc < 64; kc++)
        M = fmaxf(M, ml[((size_t)(b * 64 + kc) * P32 + p) * 2]);
    float denom = 0.f;
    for (int kc = 0; kc < 64; kc++) {
        size_t idx = ((size_t)(b * 64 + kc) * P32 + p) * 2;
        denom += ml[idx + 1] * expf(ml[idx] - M);
    }
    if (t < 64)
        wexp[t] = expf(ml[((size_t)(b * 64 + t) * P32 + p) * 2] - M);
    __syncthreads();
    float inv = 1.0f / denom;
    for (int half = 0; half < 2; half++) {
        int e = t + half * 256;
        float acc = 0.f;
        for (int kc = 0; kc < 64; kc++)
            acc += part[((size_t)(b * 64 + kc) * P32 + p) * E + e] * wexp[kc];
        wsum[((size_t)(b * P32 + p)) * E + e] = acc * inv;
    }
}

// ---------------- oatt += A(wsum)[32x64k] @ Wv[64k x 32c]  (split-K atomic) ----------------
__global__ void k_oproj(const float* __restrict__ wsum, const float* __restrict__ Wkv,
                        float* __restrict__ oatt) {
    __shared__ float Aw[32][64];
    int ct = blockIdx.x, kc = blockIdx.y, t = threadIdx.x;
    int h = ct >> 1;   // 32-col tile sits inside one head (D=64)
    {
        int rr = t >> 3, kk = (t & 7) * 8;
        int wrow = (rr >> 2) * P32 + (rr & 3) * 8 + h;
        const float* src = &wsum[(size_t)wrow * E + kc * 64 + kk];
        *(float4*)&Aw[rr][kk]     = *(const float4*)src;
        *(float4*)&Aw[rr][kk + 4] = *(const float4*)(src + 4);
    }
    __syncthreads();
#pragma unroll
    for (int rep = 0; rep < 4; rep++) {
        int idx = rep * 256 + t;
        int rr = idx >> 5, cl = idx & 31;
        int c = ct * 32 + cl;
        float acc = 0.f;
        const float* wp = &Wkv[(size_t)(kc * 64) * (2 * E) + E + c];
#pragma unroll
        for (int k = 0; k < 64; k++) acc += Aw[rr][k] * wp[(size_t)k * (2 * E)];
        atomicAdd(&oatt[rr * E + c], acc);
    }
}

// ---------------- o2 += oatt @ Wo chunk (+bg on kc==0) ----------------
__global__ void k_wo(const float* __restrict__ oatt, const float* __restrict__ Wo,
                     const float* __restrict__ bg, float* __restrict__ o2) {
    __shared__ float Aw[32][64];
    int ct = blockIdx.x, kc = blockIdx.y, t = threadIdx.x;
    {
        int rr = t >> 3, kk = (t & 7) * 8;
        const float* src = &oatt[(size_t)rr * E + kc * 64 + kk];
        *(float4*)&Aw[rr][kk]     = *(const float4*)src;
        *(float4*)&Aw[rr][kk + 4] = *(const float4*)(src + 4);
    }
    __syncthreads();
#pragma unroll
    for (int rep = 0; rep < 4; rep++) {
        int idx = rep * 256 + t;
        int rr = idx >> 5, cl = idx & 31;
        int c = ct * 32 + cl;
        float acc = (kc == 0) ? bg[rr * E + c] : 0.f;
        const float* wp = &Wo[(size_t)(kc * 64) * E + c];
#pragma unroll
        for (int k = 0; k < 64; k++) acc += Aw[rr][k] * wp[(size_t)k * E];
        atomicAdd(&o2[rr * E + c], acc);
    }
}

// ---------------- LN rows of o2 -> y ----------------
__global__ void k_ln2(const float* __restrict__ o2, const float* __restrict__ g,
                      const float* __restrict__ bb, float* __restrict__ y) {
    __shared__ float red[8];
    int r = blockIdx.x, t = threadIdx.x;
    float v0 = o2[r * E + t], v1 = o2[r * E + t + 256];
    float s = v0 + v1;
    for (int o = 32; o > 0; o >>= 1) s += __shfl_down(s, o, 64);
    if ((t & 63) == 0) red[t >> 6] = s;
    __syncthreads();
    if (t == 0) red[0] = (red[0] + red[1] + red[2] + red[3]) * (1.0f / E);
    __syncthreads();
    float mu = red[0];
    __syncthreads();
    float d0 = v0 - mu, d1 = v1 - mu;
    s = d0 * d0 + d1 * d1;
    for (int o = 32; o > 0; o >>= 1) s += __shfl_down(s, o, 64);
    if ((t & 63) == 0) red[t >> 6] = s;
    __syncthreads();
    if (t == 0) red[0] = rsqrtf((red[0] + red[1] + red[2] + red[3]) * (1.0f / E) + 1e-5f);
    __syncthreads();
    float rstd = red[0];
    y[r * E + t] = d0 * rstd * g[t] + bb[t];
    y[r * E + t + 256] = d1 * rstd * g[t + 256] + bb[t + 256];
}

// ---------------- hid += y @ W1 chunk (+b1 on kc==0), PRE-activation ----------------
__global__ void k_ffn1(const float* __restrict__ y, const float* __restrict__ W1,
                       const float* __restrict__ b1, float* __restrict__ hid) {
    __shared__ float Aw[32][64];
    int ft = blockIdx.x, kc = blockIdx.y, t = threadIdx.x;
    {
        int rr = t >> 3, kk = (t & 7) * 8;
        const float* src = &y[(size_t)rr * E + kc * 64 + kk];
        *(float4*)&Aw[rr][kk]     = *(const float4*)src;
        *(float4*)&Aw[rr][kk + 4] = *(const float4*)(src + 4);
    }
    __syncthreads();
#pragma unroll
    for (int rep = 0; rep < 4; rep++) {
        int idx = rep * 256 + t;
        int rr = idx >> 5, fcol = idx & 31;
        int f = ft * 32 + fcol;
        float acc = (kc == 0) ? b1[f] : 0.f;
        const float* wp = &W1[(size_t)(kc * 64) * FFN + f];
#pragma unroll
        for (int k = 0; k < 64; k++) acc += Aw[rr][k] * wp[(size_t)k * FFN];
        atomicAdd(&hid[rr * FFN + f], acc);
    }
}

// ---------------- out += relu(hid) @ W2 chunk (+b2+o2 on kc==0) ----------------
__global__ void k_ffn2(const float* __restrict__ hid, const float* __restrict__ W2,
                       const float* __restrict__ b2, const float* __restrict__ o2,
                       float* __restrict__ out) {
    __shared__ float Hs[32][128];
    int ct = blockIdx.x, kc = blockIdx.y, t = threadIdx.x;
    {
        int rr = t >> 3, kk = (t & 7) * 16;
        const float* src = &hid[(size_t)rr * FFN + kc * 128 + kk];
#pragma unroll
        for (int j = 0; j < 4; j++) {
            float4 v = *(const float4*)(src + j * 4);
            Hs[rr][kk + j * 4 + 0] = fmaxf(v.x, 0.f);
            Hs[rr][kk + j * 4 + 1] = fmaxf(v.y, 0.f);
            Hs[rr][kk + j * 4 + 2] = fmaxf(v.z, 0.f);
            Hs[rr][kk + j * 4 + 3] = fmaxf(v.w, 0.f);
        }
    }
    __syncthreads();
#pragma unroll
    for (int rep = 0; rep < 4; rep++) {
        int idx = rep * 256 + t;
        int rr = idx >> 5, cl = idx & 31;
        int c = ct * 32 + cl;
        float acc = (kc == 0) ? (b2[c] + o2[rr * E + c]) : 0.f;
        const float* wp = &W2[(size_t)(kc * 128) * E + c];
#pragma unroll
        for (int k = 0; k < 128; k++) acc += Hs[rr][k] * wp[(size_t)k * E];
        atomicAdd(&out[rr * E + c], acc);
    }
}

extern "C" void kernel_launch(void* const* d_in, const int* in_sizes, int n_in,
                              void* d_out, int out_size, void* d_ws, size_t ws_size,
                              hipStream_t stream) {
    const float* bg  = (const float*)d_in[0];
    const float* fv  = (const float*)d_in[1];
    const int*   fb  = (const int*)d_in[2];
    const int*   fl  = (const int*)d_in[3];
    const float* Wq  = (const float*)d_in[4];
    const float* Wkv = (const float*)d_in[5];
    const float* Wo  = (const float*)d_in[6];
    const float* rf  = (const float*)d_in[7];
    const float* lag = (const float*)d_in[8];
    const float* lab = (const float*)d_in[9];
    const float* lfg = (const float*)d_in[10];
    const float* lfb = (const float*)d_in[11];
    const float* W1  = (const float*)d_in[12];
    const float* b1  = (const float*)d_in[13];
    const float* W2  = (const float*)d_in[14];
    const float* b2  = (const float*)d_in[15];
    const int* maxlen = (const int*)d_in[16];
    float* ws = (float*)d_ws;
    int* wsi = (int*)d_ws;
    short* wall = (short*)(ws + WS_WALL);
    float* wkt = ws + WS_PART;   // WkT lives in the (not-yet-used) part region
    float* out = (float*)d_out;

    // zero-init atomic targets (oatt,o2,y,hid contiguous) and out
    hipMemsetAsync(ws + WS_OATT, 0, (size_t)(WS_PART - WS_OATT) * sizeof(float), stream);
    hipMemsetAsync(d_out, 0, (size_t)NQ * E * sizeof(float), stream);

    hipLaunchKernelGGL(k_zero, dim3(1), dim3(64), 0, stream, wsi);
    hipLaunchKernelGGL(k_hist, dim3(128), dim3(256), 0, stream, fb, wsi);
    hipLaunchKernelGGL(k_off, dim3(1), dim3(64), 0, stream, wsi);
    hipLaunchKernelGGL(k_tr, dim3(64), dim3(256), 0, stream, Wkv, wkt);
    hipLaunchKernelGGL(k_qrot, dim3(NQ), dim3(256), 0, stream, bg, Wq, rf, lag, lab, ws);
    hipLaunchKernelGGL(k_wtil, dim3(NQ * NLVL * H), dim3(64), 0, stream, wkt, rf, ws, wall);
    hipLaunchKernelGGL(k_flash, dim3(BSZ, 64), dim3(256), 0, stream,
                       fv, fl, wall, wsi, maxlen, ws + WS_PART, ws + WS_ML);
    hipLaunchKernelGGL(k_merge, dim3(BSZ * P32), dim3(256), 0, stream,
                       ws + WS_PART, ws + WS_ML, ws + WS_WSUM);
    hipLaunchKernelGGL(k_oproj, dim3(16, 8), dim3(256), 0, stream,
                       ws + WS_WSUM, Wkv, ws + WS_OATT);
    hipLaunchKernelGGL(k_wo, dim3(16, 8), dim3(256), 0, stream,
                       ws + WS_OATT, Wo, bg, ws + WS_O2);
    hipLaunchKernelGGL(k_ln2, dim3(NQ), dim3(256), 0, stream,
                       ws + WS_O2, lfg, lfb, ws + WS_Y);
    hipLaunchKernelGGL(k_ffn1, dim3(64, 8), dim3(256), 0, stream,
                       ws + WS_Y, W1, b1, ws + WS_HID);
    hipLaunchKernelGGL(k_ffn2, dim3(16, 16), dim3(256), 0, stream,
                       ws + WS_HID, W2, b2, ws + WS_O2, out);
}